// Round 2
// baseline (1109.995 us; speedup 1.0000x reference)
//
#include <hip/hip_runtime.h>
#include <math.h>

constexpr int INF_ = 128;  // IN
constexpr int H_   = 4;
constexpr int C_   = 32;
constexpr int R_   = 8;
constexpr int NB_  = 8;    // nodes per block in node_fused

// -------------------------------------------------------------------------
// CSR build: count edges per dst
// -------------------------------------------------------------------------
__global__ __launch_bounds__(256) void count_edges(
    const int* __restrict__ ei, int* __restrict__ counts, int E)
{
    int e = blockIdx.x * 256 + threadIdx.x;
    if (e >= E) return;
    int dst = ei[E + e];
    atomicAdd(&counts[dst], 1);
}

// single-block exclusive scan of counts[0..N) -> offsets[0..N]
__global__ __launch_bounds__(1024) void scan_offsets(
    const int* __restrict__ counts, int* __restrict__ offsets, int N)
{
    __shared__ int wsum[16];
    __shared__ int chunk_tot;
    const int tid  = threadIdx.x;
    const int lane = tid & 63;
    const int wid  = tid >> 6;
    int carry = 0;
    for (int base = 0; base < N; base += 1024) {
        int i = base + tid;
        int v = (i < N) ? counts[i] : 0;
        int s = v;
        #pragma unroll
        for (int d = 1; d < 64; d <<= 1) {
            int t = __shfl_up(s, d, 64);
            if (lane >= d) s += t;
        }
        if (lane == 63) wsum[wid] = s;
        __syncthreads();
        if (tid == 0) {
            int acc = 0;
            #pragma unroll
            for (int w = 0; w < 16; ++w) { int t = wsum[w]; wsum[w] = acc; acc += t; }
            chunk_tot = acc;
        }
        __syncthreads();
        int excl = carry + wsum[wid] + (s - v);
        if (i < N) offsets[i] = excl;
        carry += chunk_tot;
        __syncthreads();
    }
    if (tid == 0) offsets[N] = carry;
}

// scatter edges into dst-sorted order, packed: src | r<<17 | (dst&7)<<20
__global__ __launch_bounds__(256) void scatter_edges(
    const int* __restrict__ ei, const int* __restrict__ et,
    int* __restrict__ cursor, int* __restrict__ sorted, int E)
{
    int e = blockIdx.x * 256 + threadIdx.x;
    if (e >= E) return;
    int src = ei[e];
    int dst = ei[E + e];
    int r   = et[e];
    int pos = atomicAdd(&cursor[dst], 1);
    sorted[pos] = src | (r << 17) | ((dst & 7) << 20);
}

// -------------------------------------------------------------------------
// M_i = per-column combos of Wi with att_i, M_j likewise with att_j.
// M_i[d][r*4+h] = sum_c Wi[d][h*32+c] * natt[r*4+h][c]
// M_j[d][r*4+h] = sum_c Wj[d][h*32+c] * natt[r*4+h][32+c]
// -------------------------------------------------------------------------
__global__ __launch_bounds__(256) void prep_M(
    const float* __restrict__ Wi, const float* __restrict__ Wj,
    const float* __restrict__ natt,
    float* __restrict__ M_i, float* __restrict__ M_j)
{
    for (int idx = threadIdx.x; idx < 2 * 128 * 32; idx += 256) {
        int which = idx >> 12;         // 0: M_i, 1: M_j
        int d  = (idx >> 5) & 127;
        int rh = idx & 31;
        int h  = rh & 3;
        const float* W   = which ? Wj : Wi;
        const float* att = natt + rh * 64 + (which ? 32 : 0);
        float acc = 0.f;
        #pragma unroll
        for (int c = 0; c < 32; ++c)
            acc += W[d * 128 + h * 32 + c] * att[c];
        (which ? M_j : M_i)[d * 32 + rh] = acc;
    }
}

// -------------------------------------------------------------------------
// Fused node GEMMs: 352 output cols per node:
//   [0,128)   h_j       = x@Wj
//   [128,256) self_node = x@Wsn
//   [256,288) self_term = x@W_self   -> stored in d_out
//   [288,320) AI        = x@M_i
//   [320,352) AJ        = x@M_j
// -------------------------------------------------------------------------
__global__ __launch_bounds__(256) void fused_gemm(
    const float* __restrict__ x,
    const float* __restrict__ Wj,
    const float* __restrict__ Wsn,
    const float* __restrict__ Wself,
    const float* __restrict__ M_i,
    const float* __restrict__ M_j,
    float* __restrict__ h_j,
    float* __restrict__ self_node,
    float* __restrict__ self_term,   // = d_out
    float* __restrict__ AI,
    float* __restrict__ AJ,
    int N)
{
    __shared__ float xs[32][128];
    const int n0  = blockIdx.x * 32;
    const int tid = threadIdx.x;

    #pragma unroll
    for (int j = 0; j < 4; ++j) {
        int f4   = tid + 256 * j;
        int row  = f4 >> 5;
        int col4 = f4 & 31;
        float4 v = make_float4(0.f, 0.f, 0.f, 0.f);
        if (n0 + row < N)
            v = *(const float4*)(x + (size_t)(n0 + row) * 128 + col4 * 4);
        *(float4*)(&xs[row][col4 * 4]) = v;
    }
    __syncthreads();

    const int c_local = tid & 31;
    const int n_base  = tid >> 5;
    const int col     = blockIdx.y * 32 + c_local;   // block-uniform 32-col ranges

    const float* W; float* outb; int wcol, wstride, ostride;
    if (col < 128)      { W = Wj;    outb = h_j;       wcol = col;       wstride = 128; ostride = 128; }
    else if (col < 256) { W = Wsn;   outb = self_node; wcol = col - 128; wstride = 128; ostride = 128; }
    else if (col < 288) { W = Wself; outb = self_term; wcol = col - 256; wstride = 32;  ostride = 32;  }
    else if (col < 320) { W = M_i;   outb = AI;        wcol = col - 288; wstride = 32;  ostride = 32;  }
    else                { W = M_j;   outb = AJ;        wcol = col - 320; wstride = 32;  ostride = 32;  }

    float acc0 = 0.f, acc1 = 0.f, acc2 = 0.f, acc3 = 0.f;
    for (int k = 0; k < 128; ++k) {
        float w = W[k * wstride + wcol];
        acc0 += xs[n_base     ][k] * w;
        acc1 += xs[n_base +  8][k] * w;
        acc2 += xs[n_base + 16][k] * w;
        acc3 += xs[n_base + 24][k] * w;
    }
    if (n0 + n_base      < N) outb[(size_t)(n0 + n_base     ) * ostride + wcol] = acc0;
    if (n0 + n_base +  8 < N) outb[(size_t)(n0 + n_base +  8) * ostride + wcol] = acc1;
    if (n0 + n_base + 16 < N) outb[(size_t)(n0 + n_base + 16) * ostride + wcol] = acc2;
    if (n0 + n_base + 24 < N) outb[(size_t)(n0 + n_base + 24) * ostride + wcol] = acc3;
}

// -------------------------------------------------------------------------
// Fused per-node aggregation + relation attention tail.
// One block of 256 threads handles 8 consecutive nodes.
// -------------------------------------------------------------------------
__global__ __launch_bounds__(256) void node_fused(
    const float* __restrict__ h_j,
    const float* __restrict__ self_node,
    const float* __restrict__ AJ,        // [N,32]
    const float* __restrict__ AI,        // [N,32]
    const int*   __restrict__ offsets,   // [N+1]
    const int*   __restrict__ sorted,    // [E]
    const float* __restrict__ W_q,       // [R,128,32]
    const float* __restrict__ W_k,
    const float* __restrict__ W_v,
    const float* __restrict__ W_rel,     // [R]
    float* __restrict__ out,             // [N,32]; holds self_term on entry
    int N)
{
    __shared__ float agg[NB_][R_][128];   // 32 KB; later overlaid with q/k/v then ds
    __shared__ float den[NB_][R_][H_];    // 1 KB
    __shared__ float ai [NB_][32];        // 1 KB
    __shared__ float exs[256];            // 1 KB
    __shared__ float psi_l[NB_ * 64];     // 2 KB [n][rr][ss]
    __shared__ float mskl[NB_ * 8];       // 256 B

    const int tid = threadIdx.x;
    const int n0  = blockIdx.x * NB_;
    float* aggp = &agg[0][0][0];

    // zero accumulators, load AI tile
    for (int idx = tid; idx < NB_ * R_ * 128; idx += 256) aggp[idx] = 0.f;
    {
        float* denp = &den[0][0][0];
        if (tid < NB_ * R_ * H_) denp[tid] = 0.f;
        int nl = tid >> 5, rh = tid & 31;
        ai[nl][rh] = (n0 + nl < N) ? AI[(size_t)(n0 + nl) * 32 + rh] : 0.f;
    }
    __syncthreads();

    // ---- edge aggregation ----
    const int nend = (n0 + NB_ < N) ? n0 + NB_ : N;
    const int e0 = offsets[n0];
    const int e1 = offsets[nend];

    for (int cbase = e0; cbase < e1; cbase += 64) {
        int cnum = e1 - cbase; if (cnum > 64) cnum = 64;
        if (tid < 4 * cnum) {
            int k  = tid >> 2, h = tid & 3;
            int pk = sorted[cbase + k];
            int src = pk & 0x1FFFF;
            int r   = (pk >> 17) & 7;
            int nl  = (pk >> 20) & 7;
            float alpha = ai[nl][r * 4 + h] + AJ[(size_t)src * 32 + r * 4 + h];
            alpha = (alpha > 0.f) ? alpha : 0.2f * alpha;
            float ex = expf(alpha);
            exs[tid] = ex;
            atomicAdd(&den[nl][r][h], ex);
        }
        __syncthreads();
        {
            int sub = tid >> 7;         // 0/1: two edges in parallel
            int hc  = tid & 127;
            int h   = hc >> 5;
            for (int k = sub; k < cnum; k += 2) {
                int pk  = sorted[cbase + k];
                int src = pk & 0x1FFFF;
                int r   = (pk >> 17) & 7;
                int nl  = (pk >> 20) & 7;
                float ex  = exs[k * 4 + h];
                float val = h_j[(size_t)src * 128 + hc];
                atomicAdd(&agg[nl][r][hc], ex * val);
            }
        }
        __syncthreads();
    }

    // ---- z = agg/(den+eps) + self_node ----
    for (int idx = tid; idx < NB_ * R_ * 128; idx += 256) {
        int nl = idx >> 10;
        int rr = (idx >> 7) & 7;
        int hc = idx & 127;
        int h  = hc >> 5;
        float zv = aggp[idx] / (den[nl][rr][h] + 1e-16f);
        if (n0 + nl < N) zv += self_node[(size_t)(n0 + nl) * 128 + hc];
        aggp[idx] = zv;
    }
    __syncthreads();

    // ---- q,k,v = z @ W_{q,k,v}[r]  (8 nodes amortize weight reads) ----
    const int r = tid >> 5, c = tid & 31;
    float qv[NB_], kv[NB_], vv[NB_];
    #pragma unroll
    for (int n = 0; n < NB_; ++n) { qv[n] = 0.f; kv[n] = 0.f; vv[n] = 0.f; }
    {
        const float* wq = W_q + r * 4096 + c;
        const float* wk = W_k + r * 4096 + c;
        const float* wv = W_v + r * 4096 + c;
        for (int d = 0; d < 128; ++d) {
            float a_ = wq[d * 32], b_ = wk[d * 32], c_ = wv[d * 32];
            #pragma unroll
            for (int n = 0; n < NB_; ++n) {
                float zv = agg[n][r][d];
                qv[n] += zv * a_; kv[n] += zv * b_; vv[n] += zv * c_;
            }
        }
    }
    __syncthreads();   // all z reads done; overlay q/k/v onto agg region
    float* qs  = aggp;          // [n][r][c]
    float* ks2 = aggp + 2048;
    float* vs2 = aggp + 4096;
    #pragma unroll
    for (int n = 0; n < NB_; ++n) {
        qs [n * 256 + r * 32 + c] = qv[n];
        ks2[n * 256 + r * 32 + c] = kv[n];
        vs2[n * 256 + r * 32 + c] = vv[n];
    }
    __syncthreads();

    // ---- psi[n][rr][ss] = <q[n,rr], k[n,ss]>, softmax over ss ----
    for (int idx = tid; idx < NB_ * 64; idx += 256) {
        int n = idx >> 6, rr = (idx >> 3) & 7, ss = idx & 7;
        float p = 0.f;
        #pragma unroll
        for (int cc = 0; cc < 32; ++cc)
            p += qs[n * 256 + rr * 32 + cc] * ks2[n * 256 + ss * 32 + cc];
        psi_l[idx] = p;
    }
    __syncthreads();
    if (tid < 64) {
        int n = tid >> 3, rr = tid & 7;
        float* row = &psi_l[n * 64 + rr * 8];
        float m = -INFINITY;
        #pragma unroll
        for (int s = 0; s < 8; ++s) m = fmaxf(m, row[s]);
        float sum = 0.f;
        #pragma unroll
        for (int s = 0; s < 8; ++s) { float e = expf(row[s] - m); row[s] = e; sum += e; }
        float inv = 1.f / sum;
        #pragma unroll
        for (int s = 0; s < 8; ++s) row[s] *= inv;
    }
    __syncthreads();

    // ---- delta[n][r][c] = sum_s psi * v ; store into q region ----
    float dl[NB_];
    #pragma unroll
    for (int n = 0; n < NB_; ++n) {
        float d_ = 0.f;
        #pragma unroll
        for (int s = 0; s < 8; ++s)
            d_ += psi_l[n * 64 + r * 8 + s] * vs2[n * 256 + s * 32 + c];
        dl[n] = d_;
    }
    __syncthreads();
    #pragma unroll
    for (int n = 0; n < NB_; ++n) qs[n * 256 + r * 32 + c] = dl[n];
    __syncthreads();

    // ---- mask[n][r] = (sum_c delta != 0) ----
    if (tid < 64) {
        int n = tid >> 3, rr = tid & 7;
        float s = 0.f;
        #pragma unroll
        for (int cc = 0; cc < 32; ++cc) s += qs[n * 256 + rr * 32 + cc];
        mskl[tid] = (s != 0.f) ? 1.f : 0.f;
    }
    __syncthreads();

    // ---- out[n] = sum_r (delta + self_term*mask) * W_rel[r] ----
    {
        int n = tid >> 5, cc = tid & 31;
        if (n0 + n < N) {
            float st = out[(size_t)(n0 + n) * 32 + cc];   // self_term
            float o = 0.f;
            #pragma unroll
            for (int rr = 0; rr < 8; ++rr)
                o += (qs[n * 256 + rr * 32 + cc] + st * mskl[n * 8 + rr]) * W_rel[rr];
            out[(size_t)(n0 + n) * 32 + cc] = o;
        }
    }
}

// -------------------------------------------------------------------------
extern "C" void kernel_launch(void* const* d_in, const int* in_sizes, int n_in,
                              void* d_out, int out_size, void* d_ws, size_t ws_size,
                              hipStream_t stream)
{
    const float* x      = (const float*)d_in[0];
    const int*   ei     = (const int*)  d_in[1];   // [2,E]
    const int*   et     = (const int*)  d_in[2];   // [E]
    const float* Wj     = (const float*)d_in[3];
    const float* Wi     = (const float*)d_in[4];
    const float* natt   = (const float*)d_in[5];
    const float* W_q    = (const float*)d_in[6];
    const float* W_k    = (const float*)d_in[7];
    const float* W_v    = (const float*)d_in[8];
    const float* W_self = (const float*)d_in[9];
    const float* W_sn   = (const float*)d_in[10];
    const float* W_rel  = (const float*)d_in[11];
    float* out = (float*)d_out;

    const int N = in_sizes[0] / INF_;
    const int E = in_sizes[2];

    // workspace layout (~67 MB)
    float* ws        = (float*)d_ws;
    float* h_j       = ws;                               // N*128
    float* self_node = h_j + (size_t)N * 128;            // N*128
    float* AI        = self_node + (size_t)N * 128;      // N*32
    float* AJ        = AI + (size_t)N * 32;              // N*32
    float* M_i       = AJ + (size_t)N * 32;              // 128*32
    float* M_j       = M_i + 128 * 32;                   // 128*32
    int*   counts    = (int*)(M_j + 128 * 32);           // N+1
    int*   offsets   = counts + (N + 1);                 // N+1
    int*   cursor    = offsets + (N + 1);                // N
    int*   sorted    = cursor + N;                       // E

    // ---- CSR build ----
    hipMemsetAsync(counts, 0, (size_t)(N + 1) * sizeof(int), stream);
    count_edges<<<(E + 255) / 256, 256, 0, stream>>>(ei, counts, E);
    scan_offsets<<<1, 1024, 0, stream>>>(counts, offsets, N);
    hipMemcpyAsync(cursor, offsets, (size_t)N * sizeof(int),
                   hipMemcpyDeviceToDevice, stream);
    scatter_edges<<<(E + 255) / 256, 256, 0, stream>>>(ei, et, cursor, sorted, E);

    // ---- node feature GEMMs ----
    prep_M<<<1, 256, 0, stream>>>(Wi, Wj, natt, M_i, M_j);
    dim3 gA((N + 31) / 32, 11);
    fused_gemm<<<gA, 256, 0, stream>>>(x, Wj, W_sn, W_self, M_i, M_j,
                                       h_j, self_node, out, AI, AJ, N);

    // ---- fused aggregation + tail ----
    node_fused<<<(N + NB_ - 1) / NB_, 256, 0, stream>>>(
        h_j, self_node, AJ, AI, offsets, sorted,
        W_q, W_k, W_v, W_rel, out, N);
}

// Round 3
// 1007.332 us; speedup vs baseline: 1.1019x; 1.1019x over previous
//
#include <hip/hip_runtime.h>
#include <math.h>

constexpr int INF_ = 128;  // IN
constexpr int H_   = 4;
constexpr int C_   = 32;
constexpr int R_   = 8;
constexpr int NB_  = 8;    // nodes per block in node_fused

// -------------------------------------------------------------------------
// CSR build at 8-node GROUP granularity (order within a group is irrelevant
// to node_fused, so we only need G = ceil(N/8) segments).
// -------------------------------------------------------------------------
__global__ __launch_bounds__(256) void count_edges(
    const int* __restrict__ ei, int* __restrict__ counts, int E)
{
    int e = blockIdx.x * 256 + threadIdx.x;
    if (e >= E) return;
    int dst = ei[E + e];
    atomicAdd(&counts[dst >> 3], 1);
}

// single-block exclusive scan of counts[0..G) -> offsets[0..G]
__global__ __launch_bounds__(1024) void scan_offsets(
    const int* __restrict__ counts, int* __restrict__ offsets, int G)
{
    __shared__ int wsum[16];
    __shared__ int chunk_tot;
    const int tid  = threadIdx.x;
    const int lane = tid & 63;
    const int wid  = tid >> 6;
    int carry = 0;
    for (int base = 0; base < G; base += 1024) {
        int i = base + tid;
        int v = (i < G) ? counts[i] : 0;
        int s = v;
        #pragma unroll
        for (int d = 1; d < 64; d <<= 1) {
            int t = __shfl_up(s, d, 64);
            if (lane >= d) s += t;
        }
        if (lane == 63) wsum[wid] = s;
        __syncthreads();
        if (tid == 0) {
            int acc = 0;
            #pragma unroll
            for (int w = 0; w < 16; ++w) { int t = wsum[w]; wsum[w] = acc; acc += t; }
            chunk_tot = acc;
        }
        __syncthreads();
        int excl = carry + wsum[wid] + (s - v);
        if (i < G) offsets[i] = excl;
        carry += chunk_tot;
        __syncthreads();
    }
    if (tid == 0) offsets[G] = carry;
}

// scatter edges into group-sorted order, packed: src | r<<17 | (dst&7)<<20
__global__ __launch_bounds__(256) void scatter_edges(
    const int* __restrict__ ei, const int* __restrict__ et,
    int* __restrict__ cursor, int* __restrict__ sorted, int E)
{
    int e = blockIdx.x * 256 + threadIdx.x;
    if (e >= E) return;
    int src = ei[e];
    int dst = ei[E + e];
    int r   = et[e];
    int pos = atomicAdd(&cursor[dst >> 3], 1);
    sorted[pos] = src | (r << 17) | ((dst & 7) << 20);
}

// -------------------------------------------------------------------------
// M_i[d][r*4+h] = sum_c Wi[d][h*32+c] * natt[r*4+h][c]
// M_j[d][r*4+h] = sum_c Wj[d][h*32+c] * natt[r*4+h][32+c]
// grid 32 x 256 covers 2*128*32 = 8192 outputs
// -------------------------------------------------------------------------
__global__ __launch_bounds__(256) void prep_M(
    const float* __restrict__ Wi, const float* __restrict__ Wj,
    const float* __restrict__ natt,
    float* __restrict__ M_i, float* __restrict__ M_j)
{
    int idx = blockIdx.x * 256 + threadIdx.x;   // 0..8191
    int which = idx >> 12;         // 0: M_i, 1: M_j
    int d  = (idx >> 5) & 127;
    int rh = idx & 31;
    int h  = rh & 3;
    const float* W   = which ? Wj : Wi;
    const float* att = natt + rh * 64 + (which ? 32 : 0);
    float acc = 0.f;
    #pragma unroll
    for (int c = 0; c < 32; ++c)
        acc += W[d * 128 + h * 32 + c] * att[c];
    (which ? M_j : M_i)[d * 32 + rh] = acc;
}

// -------------------------------------------------------------------------
// Fused node GEMMs: 352 output cols per node:
//   [0,128)   h_j       = x@Wj
//   [128,256) self_node = x@Wsn
//   [256,288) self_term = x@W_self   -> stored in d_out
//   [288,320) AI        = x@M_i
//   [320,352) AJ        = x@M_j
// -------------------------------------------------------------------------
__global__ __launch_bounds__(256) void fused_gemm(
    const float* __restrict__ x,
    const float* __restrict__ Wj,
    const float* __restrict__ Wsn,
    const float* __restrict__ Wself,
    const float* __restrict__ M_i,
    const float* __restrict__ M_j,
    float* __restrict__ h_j,
    float* __restrict__ self_node,
    float* __restrict__ self_term,   // = d_out
    float* __restrict__ AI,
    float* __restrict__ AJ,
    int N)
{
    __shared__ float xs[32][128];
    const int n0  = blockIdx.x * 32;
    const int tid = threadIdx.x;

    #pragma unroll
    for (int j = 0; j < 4; ++j) {
        int f4   = tid + 256 * j;
        int row  = f4 >> 5;
        int col4 = f4 & 31;
        float4 v = make_float4(0.f, 0.f, 0.f, 0.f);
        if (n0 + row < N)
            v = *(const float4*)(x + (size_t)(n0 + row) * 128 + col4 * 4);
        *(float4*)(&xs[row][col4 * 4]) = v;
    }
    __syncthreads();

    const int c_local = tid & 31;
    const int n_base  = tid >> 5;
    const int col     = blockIdx.y * 32 + c_local;   // block-uniform 32-col ranges

    const float* W; float* outb; int wcol, wstride, ostride;
    if (col < 128)      { W = Wj;    outb = h_j;       wcol = col;       wstride = 128; ostride = 128; }
    else if (col < 256) { W = Wsn;   outb = self_node; wcol = col - 128; wstride = 128; ostride = 128; }
    else if (col < 288) { W = Wself; outb = self_term; wcol = col - 256; wstride = 32;  ostride = 32;  }
    else if (col < 320) { W = M_i;   outb = AI;        wcol = col - 288; wstride = 32;  ostride = 32;  }
    else                { W = M_j;   outb = AJ;        wcol = col - 320; wstride = 32;  ostride = 32;  }

    float acc0 = 0.f, acc1 = 0.f, acc2 = 0.f, acc3 = 0.f;
    for (int k = 0; k < 128; ++k) {
        float w = W[k * wstride + wcol];
        acc0 += xs[n_base     ][k] * w;
        acc1 += xs[n_base +  8][k] * w;
        acc2 += xs[n_base + 16][k] * w;
        acc3 += xs[n_base + 24][k] * w;
    }
    if (n0 + n_base      < N) outb[(size_t)(n0 + n_base     ) * ostride + wcol] = acc0;
    if (n0 + n_base +  8 < N) outb[(size_t)(n0 + n_base +  8) * ostride + wcol] = acc1;
    if (n0 + n_base + 16 < N) outb[(size_t)(n0 + n_base + 16) * ostride + wcol] = acc2;
    if (n0 + n_base + 24 < N) outb[(size_t)(n0 + n_base + 24) * ostride + wcol] = acc3;
}

// -------------------------------------------------------------------------
// Fused per-node aggregation + relation attention tail.
// One block of 256 threads handles 8 consecutive nodes.
// Edge loop: barrier-free, 8 edges in flight (one per half-wave), lane l
// owns hc = {l, l+32, l+64, l+96} -> all LDS ds_add_f32 conflict-free.
// -------------------------------------------------------------------------
__global__ __launch_bounds__(256) void node_fused(
    const float* __restrict__ h_j,
    const float* __restrict__ self_node,
    const float* __restrict__ AJ,        // [N,32]
    const float* __restrict__ AI,        // [N,32]
    const int*   __restrict__ offsets,   // [G+1]
    const int*   __restrict__ sorted,    // [E]
    const float* __restrict__ W_q,       // [R,128,32]
    const float* __restrict__ W_k,
    const float* __restrict__ W_v,
    const float* __restrict__ W_rel,     // [R]
    float* __restrict__ out,             // [N,32]; holds self_term on entry
    int N)
{
    __shared__ float agg[NB_][R_][128];   // 32 KB; later overlaid with q/k/v then ds
    __shared__ float den[NB_][R_][H_];    // 1 KB
    __shared__ float ai [NB_][32];        // 1 KB
    __shared__ float psi_l[NB_ * 64];     // 2 KB [n][rr][ss]
    __shared__ float mskl[NB_ * 8];       // 256 B

    const int tid = threadIdx.x;
    const int n0  = blockIdx.x * NB_;
    float* aggp = &agg[0][0][0];

    // zero accumulators, load AI tile
    for (int idx = tid; idx < NB_ * R_ * 128; idx += 256) aggp[idx] = 0.f;
    {
        float* denp = &den[0][0][0];
        denp[tid] = 0.f;                                  // NB*R*H == 256
        int nl = tid >> 5, rh = tid & 31;
        ai[nl][rh] = (n0 + nl < N) ? AI[(size_t)(n0 + nl) * 32 + rh] : 0.f;
    }
    __syncthreads();

    // ---- edge aggregation: 4 waves x 2 edges each in flight, no barriers ----
    {
        const int e0   = offsets[blockIdx.x];
        const int e1   = offsets[blockIdx.x + 1];
        const int slot = tid >> 5;        // 0..7: which of 8 concurrent edges
        const int l    = tid & 31;        // lane within half-wave

        for (int k = e0 + slot; k < e1; k += 8) {
            int pk  = sorted[k];
            int src = pk & 0x1FFFF;
            int r   = (pk >> 17) & 7;
            int nl  = (pk >> 20) & 7;
            const float* hjp = h_j + (size_t)src * 128 + l;
            float v0 = hjp[0], v1 = hjp[32], v2 = hjp[64], v3 = hjp[96];
            float4 ajv = *(const float4*)(AJ + (size_t)src * 32 + r * 4);
            const float* aip = &ai[nl][r * 4];
            float a0 = aip[0] + ajv.x; a0 = (a0 > 0.f) ? a0 : 0.2f * a0;
            float a1 = aip[1] + ajv.y; a1 = (a1 > 0.f) ? a1 : 0.2f * a1;
            float a2 = aip[2] + ajv.z; a2 = (a2 > 0.f) ? a2 : 0.2f * a2;
            float a3 = aip[3] + ajv.w; a3 = (a3 > 0.f) ? a3 : 0.2f * a3;
            float x0 = expf(a0), x1 = expf(a1), x2 = expf(a2), x3 = expf(a3);
            if (l < 4) {
                float myex = (l == 0) ? x0 : (l == 1) ? x1 : (l == 2) ? x2 : x3;
                atomicAdd(&den[nl][r][l], myex);
            }
            float* dp = &agg[nl][r][l];
            atomicAdd(dp,      x0 * v0);
            atomicAdd(dp + 32, x1 * v1);
            atomicAdd(dp + 64, x2 * v2);
            atomicAdd(dp + 96, x3 * v3);
        }
    }
    __syncthreads();

    // ---- z = agg/(den+eps) + self_node ----
    for (int idx = tid; idx < NB_ * R_ * 128; idx += 256) {
        int nl = idx >> 10;
        int rr = (idx >> 7) & 7;
        int hc = idx & 127;
        int h  = hc >> 5;
        float zv = aggp[idx] / (den[nl][rr][h] + 1e-16f);
        if (n0 + nl < N) zv += self_node[(size_t)(n0 + nl) * 128 + hc];
        aggp[idx] = zv;
    }
    __syncthreads();

    // ---- q,k,v = z @ W_{q,k,v}[r]  (8 nodes amortize weight reads) ----
    const int r = tid >> 5, c = tid & 31;
    float qv[NB_], kv[NB_], vv[NB_];
    #pragma unroll
    for (int n = 0; n < NB_; ++n) { qv[n] = 0.f; kv[n] = 0.f; vv[n] = 0.f; }
    {
        const float* wq = W_q + r * 4096 + c;
        const float* wk = W_k + r * 4096 + c;
        const float* wv = W_v + r * 4096 + c;
        for (int d = 0; d < 128; ++d) {
            float a_ = wq[d * 32], b_ = wk[d * 32], c_ = wv[d * 32];
            #pragma unroll
            for (int n = 0; n < NB_; ++n) {
                float zv = agg[n][r][d];
                qv[n] += zv * a_; kv[n] += zv * b_; vv[n] += zv * c_;
            }
        }
    }
    __syncthreads();   // all z reads done; overlay q/k/v onto agg region
    float* qs  = aggp;          // [n][r][c]
    float* ks2 = aggp + 2048;
    float* vs2 = aggp + 4096;
    #pragma unroll
    for (int n = 0; n < NB_; ++n) {
        qs [n * 256 + r * 32 + c] = qv[n];
        ks2[n * 256 + r * 32 + c] = kv[n];
        vs2[n * 256 + r * 32 + c] = vv[n];
    }
    __syncthreads();

    // ---- psi[n][rr][ss] = <q[n,rr], k[n,ss]>, softmax over ss ----
    for (int idx = tid; idx < NB_ * 64; idx += 256) {
        int n = idx >> 6, rr = (idx >> 3) & 7, ss = idx & 7;
        float p = 0.f;
        #pragma unroll
        for (int cc = 0; cc < 32; ++cc)
            p += qs[n * 256 + rr * 32 + cc] * ks2[n * 256 + ss * 32 + cc];
        psi_l[idx] = p;
    }
    __syncthreads();
    if (tid < 64) {
        int n = tid >> 3, rr = tid & 7;
        float* row = &psi_l[n * 64 + rr * 8];
        float m = -INFINITY;
        #pragma unroll
        for (int s = 0; s < 8; ++s) m = fmaxf(m, row[s]);
        float sum = 0.f;
        #pragma unroll
        for (int s = 0; s < 8; ++s) { float e = expf(row[s] - m); row[s] = e; sum += e; }
        float inv = 1.f / sum;
        #pragma unroll
        for (int s = 0; s < 8; ++s) row[s] *= inv;
    }
    __syncthreads();

    // ---- delta[n][r][c] = sum_s psi * v ; store into q region ----
    float dl[NB_];
    #pragma unroll
    for (int n = 0; n < NB_; ++n) {
        float d_ = 0.f;
        #pragma unroll
        for (int s = 0; s < 8; ++s)
            d_ += psi_l[n * 64 + r * 8 + s] * vs2[n * 256 + s * 32 + c];
        dl[n] = d_;
    }
    __syncthreads();
    #pragma unroll
    for (int n = 0; n < NB_; ++n) qs[n * 256 + r * 32 + c] = dl[n];
    __syncthreads();

    // ---- mask[n][r] = (sum_c delta != 0) ----
    if (tid < 64) {
        int n = tid >> 3, rr = tid & 7;
        float s = 0.f;
        #pragma unroll
        for (int cc = 0; cc < 32; ++cc) s += qs[n * 256 + rr * 32 + cc];
        mskl[tid] = (s != 0.f) ? 1.f : 0.f;
    }
    __syncthreads();

    // ---- out[n] = sum_r (delta + self_term*mask) * W_rel[r] ----
    {
        int n = tid >> 5, cc = tid & 31;
        if (n0 + n < N) {
            float st = out[(size_t)(n0 + n) * 32 + cc];   // self_term
            float o = 0.f;
            #pragma unroll
            for (int rr = 0; rr < 8; ++rr)
                o += (qs[n * 256 + rr * 32 + cc] + st * mskl[n * 8 + rr]) * W_rel[rr];
            out[(size_t)(n0 + n) * 32 + cc] = o;
        }
    }
}

// -------------------------------------------------------------------------
extern "C" void kernel_launch(void* const* d_in, const int* in_sizes, int n_in,
                              void* d_out, int out_size, void* d_ws, size_t ws_size,
                              hipStream_t stream)
{
    const float* x      = (const float*)d_in[0];
    const int*   ei     = (const int*)  d_in[1];   // [2,E]
    const int*   et     = (const int*)  d_in[2];   // [E]
    const float* Wj     = (const float*)d_in[3];
    const float* Wi     = (const float*)d_in[4];
    const float* natt   = (const float*)d_in[5];
    const float* W_q    = (const float*)d_in[6];
    const float* W_k    = (const float*)d_in[7];
    const float* W_v    = (const float*)d_in[8];
    const float* W_self = (const float*)d_in[9];
    const float* W_sn   = (const float*)d_in[10];
    const float* W_rel  = (const float*)d_in[11];
    float* out = (float*)d_out;

    const int N = in_sizes[0] / INF_;
    const int E = in_sizes[2];
    const int G = (N + NB_ - 1) / NB_;   // 8-node groups

    // workspace layout (~67 MB)
    float* ws        = (float*)d_ws;
    float* h_j       = ws;                               // N*128
    float* self_node = h_j + (size_t)N * 128;            // N*128
    float* AI        = self_node + (size_t)N * 128;      // N*32
    float* AJ        = AI + (size_t)N * 32;              // N*32
    float* M_i       = AJ + (size_t)N * 32;              // 128*32
    float* M_j       = M_i + 128 * 32;                   // 128*32
    int*   counts    = (int*)(M_j + 128 * 32);           // G+1
    int*   offsets   = counts + (G + 1);                 // G+1
    int*   cursor    = offsets + (G + 1);                // G
    int*   sorted    = cursor + G;                       // E

    // ---- CSR build (group granularity) ----
    hipMemsetAsync(counts, 0, (size_t)(G + 1) * sizeof(int), stream);
    count_edges<<<(E + 255) / 256, 256, 0, stream>>>(ei, counts, E);
    scan_offsets<<<1, 1024, 0, stream>>>(counts, offsets, G);
    hipMemcpyAsync(cursor, offsets, (size_t)G * sizeof(int),
                   hipMemcpyDeviceToDevice, stream);
    scatter_edges<<<(E + 255) / 256, 256, 0, stream>>>(ei, et, cursor, sorted, E);

    // ---- node feature GEMMs ----
    prep_M<<<32, 256, 0, stream>>>(Wi, Wj, natt, M_i, M_j);
    dim3 gA((N + 31) / 32, 11);
    fused_gemm<<<gA, 256, 0, stream>>>(x, Wj, W_sn, W_self, M_i, M_j,
                                       h_j, self_node, out, AI, AJ, N);

    // ---- fused aggregation + tail ----
    node_fused<<<G, 256, 0, stream>>>(
        h_j, self_node, AJ, AI, offsets, sorted,
        W_q, W_k, W_v, W_rel, out, N);
}